// Round 1
// baseline (533.837 us; speedup 1.0000x reference)
//
#include <hip/hip_runtime.h>
#include <hip/hip_bf16.h>
#include <stdint.h>

// Problem constants (B=2, L=2048 -> T=4096 tokens)
#define T_TOK 4096
#define DDIM  1024
#define IDIM  4096
#define NEXP  8
// padded row count for gathered matrices (worst-case tile overhang)
#define GROWS (T_TOK*2 + 128)

typedef __attribute__((ext_vector_type(8))) short bfrag;   // 8 bf16 (4 VGPR)
typedef __attribute__((ext_vector_type(4))) float f32x4;   // MFMA accum

__device__ __forceinline__ unsigned short f2bf(float x) {
    unsigned int u = __float_as_uint(x);
    unsigned int r = u + 0x7FFFu + ((u >> 16) & 1u);   // RNE
    return (unsigned short)(r >> 16);
}
__device__ __forceinline__ float bf2f(unsigned short h) {
    return __uint_as_float(((unsigned int)h) << 16);
}

// ---------------------------------------------------------------------------
// K1: per-token layernorm stats + xhat (bf16), fp32 router logits, top-2,
//     softmax -> per-slot weights; builds per-expert token lists via atomics.
// ---------------------------------------------------------------------------
__global__ __launch_bounds__(256) void router_kernel(
    const float* __restrict__ x,
    const float* __restrict__ rng, const float* __restrict__ rnb,
    const float* __restrict__ rw,  const float* __restrict__ rb,
    unsigned short* __restrict__ xhat,
    int* __restrict__ counts, int* __restrict__ tok_slot,
    float* __restrict__ wslot)
{
    const int t = blockIdx.x;
    const int tid = threadIdx.x;
    const int lane = tid & 63, wid = tid >> 6;

    float4 v = *(const float4*)(x + (size_t)t * DDIM + tid * 4);
    float s1 = v.x + v.y + v.z + v.w;
    float s2 = v.x*v.x + v.y*v.y + v.z*v.z + v.w*v.w;
    #pragma unroll
    for (int m = 32; m; m >>= 1) { s1 += __shfl_xor(s1, m, 64); s2 += __shfl_xor(s2, m, 64); }

    __shared__ float red[8];
    __shared__ float pl[4][8];
    __shared__ float bcast[2];
    if (lane == 0) { red[wid] = s1; red[wid + 4] = s2; }
    __syncthreads();
    if (tid == 0) {
        float S1 = red[0] + red[1] + red[2] + red[3];
        float S2 = red[4] + red[5] + red[6] + red[7];
        float mean = S1 * (1.f / 1024.f);
        float var  = S2 * (1.f / 1024.f) - mean * mean;
        bcast[0] = mean; bcast[1] = rsqrtf(var + 1e-5f);
    }
    __syncthreads();
    const float mean = bcast[0], rinv = bcast[1];

    float4 xh = { (v.x - mean) * rinv, (v.y - mean) * rinv,
                  (v.z - mean) * rinv, (v.w - mean) * rinv };
    ushort4 hx = { f2bf(xh.x), f2bf(xh.y), f2bf(xh.z), f2bf(xh.w) };
    *(ushort4*)(xhat + (size_t)t * DDIM + tid * 4) = hx;

    // router layernorm affine + logits (kept fp32 to match reference top-k)
    float4 g = *(const float4*)(rng + tid * 4);
    float4 b = *(const float4*)(rnb + tid * 4);
    float4 nm = { xh.x*g.x + b.x, xh.y*g.y + b.y, xh.z*g.z + b.z, xh.w*g.w + b.w };
    float p[8];
    #pragma unroll
    for (int e = 0; e < 8; e++) {
        float4 w = *(const float4*)(rw + e * DDIM + tid * 4);
        p[e] = nm.x*w.x + nm.y*w.y + nm.z*w.z + nm.w*w.w;
    }
    #pragma unroll
    for (int m = 32; m; m >>= 1) {
        #pragma unroll
        for (int e = 0; e < 8; e++) p[e] += __shfl_xor(p[e], m, 64);
    }
    if (lane == 0) {
        #pragma unroll
        for (int e = 0; e < 8; e++) pl[wid][e] = p[e];
    }
    __syncthreads();
    if (tid == 0) {
        float l[8];
        #pragma unroll
        for (int e = 0; e < 8; e++) l[e] = pl[0][e] + pl[1][e] + pl[2][e] + pl[3][e] + rb[e];
        int e0 = 0; float v0 = l[0];
        for (int e = 1; e < 8; e++) if (l[e] > v0) { v0 = l[e]; e0 = e; }
        int e1 = (e0 == 0) ? 1 : 0; float v1 = l[e1];
        for (int e = 0; e < 8; e++) if (e != e0 && l[e] > v1) { v1 = l[e]; e1 = e; }
        float ex = expf(v1 - v0);
        float w0 = 1.f / (1.f + ex);
        float w1 = ex * w0;
        int p0 = atomicAdd(&counts[e0], 1);
        tok_slot[e0 * T_TOK + p0] = (t << 1);
        int p1 = atomicAdd(&counts[e1], 1);
        tok_slot[e1 * T_TOK + p1] = (t << 1) | 1;
        wslot[t * 2]     = w0;
        wslot[t * 2 + 1] = w1;
    }
}

// K2: tiny exclusive prefix over 8 expert counts
__global__ void prefix_kernel(const int* __restrict__ counts, int* __restrict__ offs)
{
    if (threadIdx.x == 0) {
        int a = 0;
        for (int e = 0; e < 8; e++) { offs[e] = a; a += counts[e]; }
    }
}

// ---------------------------------------------------------------------------
// K3: build compacted per-expert A matrix: Agath[off[e]+pos][d] =
//     bf16( xhat[t][d]*ln_g[e][d] + ln_b[e][d] ), plus rowinfo for scatter.
// ---------------------------------------------------------------------------
__global__ __launch_bounds__(256) void gather_kernel(
    const unsigned short* __restrict__ xhat,
    const float* __restrict__ lng, const float* __restrict__ lnb,
    const int* __restrict__ counts, const int* __restrict__ offs,
    const int* __restrict__ tok_slot,
    unsigned short* __restrict__ Agath, int* __restrict__ rowinfo)
{
    const int e = blockIdx.y, pos = blockIdx.x;
    if (pos >= counts[e]) return;
    const int grow = offs[e] + pos;
    const int info = tok_slot[e * T_TOK + pos];
    if (threadIdx.x == 0) rowinfo[grow] = info;
    const int t = info >> 1;
    const int d = threadIdx.x * 4;
    ushort4 hx = *(const ushort4*)(xhat + (size_t)t * DDIM + d);
    float4 g = *(const float4*)(lng + (size_t)e * DDIM + d);
    float4 b = *(const float4*)(lnb + (size_t)e * DDIM + d);
    ushort4 o = { f2bf(bf2f(hx.x) * g.x + b.x),
                  f2bf(bf2f(hx.y) * g.y + b.y),
                  f2bf(bf2f(hx.z) * g.z + b.z),
                  f2bf(bf2f(hx.w) * g.w + b.w) };
    *(ushort4*)(Agath + (size_t)grow * DDIM + d) = o;
}

// ---------------------------------------------------------------------------
// GEMM: C[128x128] tile = A(bf16 rows, [*][Kd]) x W(fp32 [E][Kd][Nd]).
// LDS layout: [row][k] bf16, row stride 72 ushort (=144B, +16B pad) ->
// conflict-free b128 fragment reads. EPI=0: +b1, exact GELU -> H (bf16).
// EPI=1: +b2, *combine-weight, atomicAdd scatter into out.
// ---------------------------------------------------------------------------
template<int EPI>
__global__ __launch_bounds__(256) void gemm_kernel(
    const unsigned short* __restrict__ Asrc,
    const float* __restrict__ Wsrc,
    const float* __restrict__ bias,
    const int* __restrict__ counts,
    const int* __restrict__ offs,
    const int* __restrict__ rowinfo,
    const float* __restrict__ wslot,
    unsigned short* __restrict__ Hout,
    float* __restrict__ Out,
    int Kd, int Nd)
{
    const int e  = blockIdx.z;
    const int ne = counts[e];
    const int mt = blockIdx.y;
    if (mt * 128 >= ne) return;
    const int n0 = blockIdx.x * 128;
    const int growbase = offs[e] + mt * 128;
    const int tid  = threadIdx.x;
    const int lane = tid & 63;
    const int wm = (tid >> 7) & 1;
    const int wn = (tid >> 6) & 1;

    __shared__ unsigned short As[128 * 72];
    __shared__ unsigned short Bs[128 * 72];

    f32x4 acc[4][4];
    #pragma unroll
    for (int i = 0; i < 4; i++)
        #pragma unroll
        for (int j = 0; j < 4; j++)
            acc[i][j] = (f32x4){0.f, 0.f, 0.f, 0.f};

    const float* W = Wsrc + (size_t)e * Kd * Nd;

    for (int k0 = 0; k0 < Kd; k0 += 64) {
        __syncthreads();
        // ---- stage A: 128 rows x 64 k of bf16 (16B chunks, coalesced) ----
        #pragma unroll
        for (int c = 0; c < 4; c++) {
            int ci = c * 256 + tid;
            int row = ci >> 3, s = ci & 7;
            int4 v = *(const int4*)(Asrc + (size_t)(growbase + row) * Kd + k0 + s * 8);
            *(int4*)((char*)As + row * 144 + s * 16) = v;
        }
        // ---- stage B: 64 k x 128 n fp32 -> Bs[n][k] bf16 (transpose+convert)
        #pragma unroll
        for (int q = 0; q < 2; q++) {
            int bi = q * 256 + tid;
            int nb = bi & 63;          // n-pair index
            int kb = bi >> 6;          // k-group of 8
            int n  = nb * 2;
            const float* wp = W + (size_t)(k0 + kb * 8) * Nd + n0 + n;
            float2 f[8];
            #pragma unroll
            for (int r = 0; r < 8; r++) f[r] = *(const float2*)(wp + (size_t)r * Nd);
            int4 va, vb;
            va.x = (int)(((unsigned)f2bf(f[0].x)) | ((unsigned)f2bf(f[1].x) << 16));
            va.y = (int)(((unsigned)f2bf(f[2].x)) | ((unsigned)f2bf(f[3].x) << 16));
            va.z = (int)(((unsigned)f2bf(f[4].x)) | ((unsigned)f2bf(f[5].x) << 16));
            va.w = (int)(((unsigned)f2bf(f[6].x)) | ((unsigned)f2bf(f[7].x) << 16));
            vb.x = (int)(((unsigned)f2bf(f[0].y)) | ((unsigned)f2bf(f[1].y) << 16));
            vb.y = (int)(((unsigned)f2bf(f[2].y)) | ((unsigned)f2bf(f[3].y) << 16));
            vb.z = (int)(((unsigned)f2bf(f[4].y)) | ((unsigned)f2bf(f[5].y) << 16));
            vb.w = (int)(((unsigned)f2bf(f[6].y)) | ((unsigned)f2bf(f[7].y) << 16));
            *(int4*)((char*)Bs + (size_t)n       * 144 + kb * 16) = va;
            *(int4*)((char*)Bs + (size_t)(n + 1) * 144 + kb * 16) = vb;
        }
        __syncthreads();
        // ---- compute: 2 k-steps of 32, 16 MFMA each, per wave ----
        #pragma unroll
        for (int kk = 0; kk < 2; kk++) {
            bfrag av[4], bv[4];
            #pragma unroll
            for (int i = 0; i < 4; i++)
                av[i] = *(const bfrag*)((const char*)As +
                         (wm * 64 + i * 16 + (lane & 15)) * 144 + kk * 64 + ((lane >> 4) << 4));
            #pragma unroll
            for (int j = 0; j < 4; j++)
                bv[j] = *(const bfrag*)((const char*)Bs +
                         (wn * 64 + j * 16 + (lane & 15)) * 144 + kk * 64 + ((lane >> 4) << 4));
            #pragma unroll
            for (int i = 0; i < 4; i++)
                #pragma unroll
                for (int j = 0; j < 4; j++)
                    acc[i][j] = __builtin_amdgcn_mfma_f32_16x16x32_bf16(av[i], bv[j], acc[i][j], 0, 0, 0);
        }
    }

    // ---- epilogue (C/D layout: col = lane&15, row = (lane>>4)*4 + reg) ----
    const float* bg = bias + (size_t)e * Nd;
    #pragma unroll
    for (int i = 0; i < 4; i++) {
        #pragma unroll
        for (int r = 0; r < 4; r++) {
            int mrow = wm * 64 + i * 16 + ((lane >> 4) << 2) + r;
            int pos = mt * 128 + mrow;
            if (pos >= ne) continue;
            if constexpr (EPI == 0) {
                size_t rowoff = (size_t)(growbase + mrow) * Nd;
                #pragma unroll
                for (int j = 0; j < 4; j++) {
                    int col = n0 + wn * 64 + j * 16 + (lane & 15);
                    float y = acc[i][j][r] + bg[col];
                    float gl = 0.5f * y * (1.f + erff(y * 0.70710678118654752f));
                    Hout[rowoff + col] = f2bf(gl);
                }
            } else {
                int info = rowinfo[growbase + mrow];
                float wg = wslot[info];
                float* op = Out + (size_t)(info >> 1) * Nd;
                #pragma unroll
                for (int j = 0; j < 4; j++) {
                    int col = n0 + wn * 64 + j * 16 + (lane & 15);
                    float y = acc[i][j][r] + bg[col];
                    atomicAdd(op + col, wg * y);   // exactly 2 adds/elem -> deterministic
                }
            }
        }
    }
}

// ---------------------------------------------------------------------------
extern "C" void kernel_launch(void* const* d_in, const int* in_sizes, int n_in,
                              void* d_out, int out_size, void* d_ws, size_t ws_size,
                              hipStream_t stream)
{
    (void)in_sizes; (void)n_in; (void)ws_size;
    const float* hidden   = (const float*)d_in[0];
    const float* rn_g     = (const float*)d_in[1];
    const float* rn_b     = (const float*)d_in[2];
    const float* router_w = (const float*)d_in[3];
    const float* router_b = (const float*)d_in[4];
    const float* ln_g     = (const float*)d_in[5];
    const float* ln_b     = (const float*)d_in[6];
    const float* w1       = (const float*)d_in[7];
    const float* b1       = (const float*)d_in[8];
    const float* w2       = (const float*)d_in[9];
    const float* b2       = (const float*)d_in[10];
    float* out = (float*)d_out;

    // workspace layout (bytes): total ~93.8 MB
    char* ws = (char*)d_ws;
    unsigned short* xhat   = (unsigned short*)ws;                 //  8,388,608
    unsigned short* Agath  = (unsigned short*)(ws + 8388608);     // 17,039,360 (GROWS x D)
    unsigned short* H      = (unsigned short*)(ws + 25427968);    // 68,157,440 (GROWS x I)
    int*   counts   = (int*)(ws + 93585408);                      // 32
    int*   offs     = (int*)(ws + 93585440);                      // 32
    int*   tok_slot = (int*)(ws + 93585472);                      // 131,072
    int*   rowinfo  = (int*)(ws + 93716544);                      // 33,280
    float* wslot    = (float*)(ws + 93749824);                    // 32,768

    hipMemsetAsync(counts, 0, 64, stream);                        // counts+offs
    hipMemsetAsync(d_out, 0, (size_t)out_size * sizeof(float), stream);

    router_kernel<<<T_TOK, 256, 0, stream>>>(hidden, rn_g, rn_b, router_w, router_b,
                                             xhat, counts, tok_slot, wslot);
    prefix_kernel<<<1, 64, 0, stream>>>(counts, offs);
    gather_kernel<<<dim3(T_TOK, NEXP), 256, 0, stream>>>(xhat, ln_g, ln_b, counts, offs,
                                                         tok_slot, Agath, rowinfo);
    // GEMM1: [rows x 1024] x [1024 x 4096] + b1, GELU -> H
    gemm_kernel<0><<<dim3(IDIM / 128, 32, NEXP), 256, 0, stream>>>(
        Agath, w1, b1, counts, offs, rowinfo, wslot, H, nullptr, DDIM, IDIM);
    // GEMM2: [rows x 4096] x [4096 x 1024] + b2, *w, scatter-add -> out
    gemm_kernel<1><<<dim3(DDIM / 128, 32, NEXP), 256, 0, stream>>>(
        H, w2, b2, counts, offs, rowinfo, wslot, nullptr, out, IDIM, DDIM);
}